// Round 1
// baseline (44254.987 us; speedup 1.0000x reference)
//
#include <hip/hip_runtime.h>
#include <hip/hip_bf16.h>

// LSTM persistent-kernel implementation for MI355X (gfx950).
// S=2048 sequential steps; 64 WGs (1/CU), WG j owns hidden slice [8j, 8j+8).
// Weights (32 gate rows x 1024 K) cached in LDS as bf16 for the whole kernel.
// h exchanged via double-buffered bf16 global buffer + per-(step,WG) flags.

#define SEQ 2048
#define BAT 64
#define DIN 512
#define HID 512
#define NWG 64
#define HS  8          // hidden units per WG
#define NG  32         // gate rows per WG (4*HS)
#define XSS 520        // xs row stride in bf16 elems (+8 pad: 4-bank row shift, conflict-free b128)
#define WSS 520

typedef short v8s __attribute__((ext_vector_type(8)));   // 8 x bf16 (4 VGPRs)
typedef float v4f __attribute__((ext_vector_type(4)));   // MFMA accumulator

__device__ __forceinline__ unsigned short f2bf(float f) {
  unsigned int u = __builtin_bit_cast(unsigned int, f);
  u += 0x7fffu + ((u >> 16) & 1u);   // round-to-nearest-even
  return (unsigned short)(u >> 16);
}
__device__ __forceinline__ float sigm(float v)  { return 1.0f / (1.0f + __expf(-v)); }
__device__ __forceinline__ float tanha(float v) { return 1.0f - 2.0f / (__expf(2.0f * v) + 1.0f); }

__global__ __launch_bounds__(256, 1) void lstm_persistent(
    const float* __restrict__ x, const float* __restrict__ Wih,
    const float* __restrict__ Whh, const float* __restrict__ bih,
    const float* __restrict__ bhh, float* __restrict__ out,
    int* __restrict__ flags, unsigned short* __restrict__ hbuf)
{
  __shared__ unsigned short xs[BAT * XSS];     // 66,560 B: x_t or h_{t-1} as bf16
  __shared__ unsigned short Wx[NG * WSS];      // 33,280 B: W_ih slice
  __shared__ unsigned short Wh[NG * WSS];      // 33,280 B: W_hh slice
  __shared__ float gl[BAT * (NG + 1)];         //  8,448 B: gate pre-activations
  __shared__ float cs[BAT * HS];               //  2,048 B: c state (fp32)
  __shared__ float bias[NG];

  const int tid = threadIdx.x;
  const int j   = blockIdx.x;
  const int hb  = j * HS;

  // ---- one-time: load weight slices (rows: c = g*8+hh -> global row g*512+hb+hh) ----
  for (int idx = tid; idx < NG * 128; idx += 256) {
    int r = idx >> 7;              // 0..31
    int k = (idx & 127) * 4;       // 0..508
    int grow = (r >> 3) * HID + hb + (r & 7);
    float4 a = *(const float4*)(Wih + (size_t)grow * DIN + k);
    float4 b = *(const float4*)(Whh + (size_t)grow * HID + k);
    *(ushort4*)(Wx + r * WSS + k) = make_ushort4(f2bf(a.x), f2bf(a.y), f2bf(a.z), f2bf(a.w));
    *(ushort4*)(Wh + r * WSS + k) = make_ushort4(f2bf(b.x), f2bf(b.y), f2bf(b.z), f2bf(b.w));
  }
  if (tid < NG) {
    int grow = (tid >> 3) * HID + hb + (tid & 7);
    bias[tid] = bih[grow] + bhh[grow];
  }
  for (int i = tid; i < BAT * HS; i += 256) cs[i] = 0.0f;
  __syncthreads();

  const int wv = tid >> 6, ln = tid & 63, l15 = ln & 15, lg = ln >> 4;
  const int m0 = wv * 16;        // wave owns batch rows [m0, m0+16)
  const unsigned short* aptr = xs + (m0 + l15) * XSS + lg * 8;

  for (int t = 0; t < SEQ; ++t) {
    // ---- stage x[t] -> xs as bf16 (coalesced float4 reads) ----
    for (int it = tid; it < BAT * DIN / 4; it += 256) {
      int m = it >> 7;
      int k = (it & 127) * 4;
      float4 v = *(const float4*)(x + ((size_t)t * BAT + m) * DIN + k);
      *(ushort4*)(xs + m * XSS + k) = make_ushort4(f2bf(v.x), f2bf(v.y), f2bf(v.z), f2bf(v.w));
    }
    __syncthreads();

    v4f acc0 = {0.f, 0.f, 0.f, 0.f}, acc1 = {0.f, 0.f, 0.f, 0.f};
    // ---- phase X: gates += x_t @ W_ih_slice^T  (overlaps with h not yet ready) ----
    {
      const unsigned short* b0 = Wx + l15 * WSS + lg * 8;
      const unsigned short* b1 = Wx + (16 + l15) * WSS + lg * 8;
      #pragma unroll
      for (int kc = 0; kc < DIN; kc += 32) {
        v8s a  = *(const v8s*)(aptr + kc);
        v8s w0 = *(const v8s*)(b0 + kc);
        v8s w1 = *(const v8s*)(b1 + kc);
        acc0 = __builtin_amdgcn_mfma_f32_16x16x32_bf16(a, w0, acc0, 0, 0, 0);
        acc1 = __builtin_amdgcn_mfma_f32_16x16x32_bf16(a, w1, acc1, 0, 0, 0);
      }
    }
    if (t > 0) {
      // ---- wait for all 64 h-chunks of step t-1 (wave0 polls, one flag per lane) ----
      if (wv == 0) {
        int fidx = (t - 1) * NWG + ln;
        while (__hip_atomic_load(flags + fidx, __ATOMIC_ACQUIRE,
                                 __HIP_MEMORY_SCOPE_AGENT) != t) {
          __builtin_amdgcn_s_sleep(2);
        }
      }
      __syncthreads();   // also guards xs reuse (phase-X reads done)
      // ---- stage h_{t-1} -> xs (bf16, 16B loads) ----
      const unsigned short* hsrc = hbuf + ((size_t)((t - 1) & 1)) * (BAT * HID);
      for (int it = tid; it < BAT * HID / 8; it += 256) {
        int m = it >> 6;
        int k = (it & 63) * 8;
        uint4 v = *(const uint4*)(hsrc + m * HID + k);
        *(uint4*)(xs + m * XSS + k) = v;
      }
      __syncthreads();
      // ---- phase H: gates += h_{t-1} @ W_hh_slice^T ----
      const unsigned short* b0 = Wh + l15 * WSS + lg * 8;
      const unsigned short* b1 = Wh + (16 + l15) * WSS + lg * 8;
      #pragma unroll
      for (int kc = 0; kc < HID; kc += 32) {
        v8s a  = *(const v8s*)(aptr + kc);
        v8s w0 = *(const v8s*)(b0 + kc);
        v8s w1 = *(const v8s*)(b1 + kc);
        acc0 = __builtin_amdgcn_mfma_f32_16x16x32_bf16(a, w0, acc0, 0, 0, 0);
        acc1 = __builtin_amdgcn_mfma_f32_16x16x32_bf16(a, w1, acc1, 0, 0, 0);
      }
    }
    // ---- epilogue: C-frags -> gl.  C/D layout: col=lane&15, row=(lane>>4)*4+reg ----
    {
      int mrow = m0 + lg * 4;
      #pragma unroll
      for (int r = 0; r < 4; ++r) {
        gl[(mrow + r) * (NG + 1) + l15]      = acc0[r];
        gl[(mrow + r) * (NG + 1) + 16 + l15] = acc1[r];
      }
    }
    __syncthreads();
    // ---- elementwise cell update (fp32), outputs, publish h chunk ----
    unsigned short* hdst = hbuf + ((size_t)(t & 1)) * (BAT * HID);
    for (int cell = tid; cell < BAT * HS; cell += 256) {
      int m = cell >> 3, hh = cell & 7;
      const float* gr = gl + m * (NG + 1);
      float gi = gr[hh]      + bias[hh];
      float gf = gr[8 + hh]  + bias[8 + hh];
      float gg = gr[16 + hh] + bias[16 + hh];
      float go = gr[24 + hh] + bias[24 + hh];
      float c  = sigm(gf) * cs[cell] + sigm(gi) * tanha(gg);
      cs[cell] = c;
      float h  = sigm(go) * tanha(c);
      size_t o = ((size_t)t * BAT + m) * HID + hb + hh;
      out[o] = h;
      out[(size_t)SEQ * BAT * HID + o] = c;
      hdst[m * HID + hb + hh] = f2bf(h);
    }
    __threadfence();        // make h stores visible agent-wide before flag
    __syncthreads();
    if (tid == 0) {
      __hip_atomic_store(flags + t * NWG + j, t + 1, __ATOMIC_RELEASE,
                         __HIP_MEMORY_SCOPE_AGENT);
    }
  }
}

extern "C" void kernel_launch(void* const* d_in, const int* in_sizes, int n_in,
                              void* d_out, int out_size, void* d_ws, size_t ws_size,
                              hipStream_t stream) {
  const float* x   = (const float*)d_in[0];
  const float* Wih = (const float*)d_in[1];
  const float* Whh = (const float*)d_in[2];
  const float* bih = (const float*)d_in[3];
  const float* bhh = (const float*)d_in[4];
  float* out = (float*)d_out;

  int* flags = (int*)d_ws;                                        // SEQ*NWG ints = 512 KB
  unsigned short* hbuf =
      (unsigned short*)((char*)d_ws + (size_t)SEQ * NWG * sizeof(int));  // 2*64*512 bf16 = 128 KB

  // Clear flags (don't rely on 0xAA poison between graph replays).
  hipMemsetAsync(d_ws, 0, (size_t)SEQ * NWG * sizeof(int), stream);

  hipLaunchKernelGGL(lstm_persistent, dim3(NWG), dim3(256), 0, stream,
                     x, Wih, Whh, bih, bhh, out, flags, hbuf);
}